// Round 1
// baseline (1998.868 us; speedup 1.0000x reference)
//
#include <hip/hip_runtime.h>

typedef unsigned short u16;
typedef __attribute__((ext_vector_type(8))) short bf16x8;
typedef __attribute__((ext_vector_type(4))) float f32x4;

#define B_ 8
#define T_ 2048
#define M_ 16384          // B*T
#define N_ 3072           // 3*H
#define H_ 1024

__device__ __forceinline__ u16 f2bf(float f) {
    union { float f; unsigned u; } v; v.f = f;
    unsigned r = v.u + 0x7FFFu + ((v.u >> 16) & 1u);   // RNE
    return (u16)(r >> 16);
}
__device__ __forceinline__ float bf2f(u16 s) {
    union { unsigned u; float f; } v; v.u = ((unsigned)s) << 16;
    return v.f;
}

__device__ __forceinline__ void gload_lds16(const void* g, void* l) {
    __builtin_amdgcn_global_load_lds(
        (const __attribute__((address_space(1))) unsigned int*)g,
        (__attribute__((address_space(3))) unsigned int*)l,
        16, 0, 0);
}

// Build bf16 x1 [16384][1600] = concat(pa, st, md) zero-padded 1591..1600
__global__ void concat_cast(const float* __restrict__ pa, const float* __restrict__ st,
                            const float* __restrict__ md, u16* __restrict__ x) {
    const int m = blockIdx.x;
    const float* pam = pa + (size_t)m * 695;
    const float* stm = st + (size_t)m * 812;
    const float* mdm = md + (size_t)m * 84;
    u16* xm = x + (size_t)m * 1600;
    for (int d = threadIdx.x; d < 1600; d += 256) {
        float v;
        if (d < 695)       v = pam[d];
        else if (d < 1507) v = stm[d - 695];
        else if (d < 1591) v = mdm[d - 1507];
        else               v = 0.f;
        xm[d] = f2bf(v);
    }
}

// Wt[n][k] = bf16(W[k][n]), K rows valid, zero-pad to Kp
__global__ void wtrans(const float* __restrict__ W, u16* __restrict__ Wt, int K, int Kp) {
    __shared__ float tile[32][33];
    const int n0 = blockIdx.x << 5;
    const int k0 = blockIdx.y << 5;
    const int tx = threadIdx.x & 31, ty = threadIdx.x >> 5;   // 32 x 8
    #pragma unroll
    for (int i = 0; i < 32; i += 8) {
        int k = k0 + ty + i;
        tile[ty + i][tx] = (k < K) ? W[(size_t)k * N_ + n0 + tx] : 0.f;
    }
    __syncthreads();
    #pragma unroll
    for (int i = 0; i < 32; i += 8) {
        int n = n0 + ty + i;
        Wt[(size_t)n * Kp + k0 + tx] = f2bf(tile[tx][ty + i]);
    }
}

// C[m][n] = sum_k A[m][k]*Bt[n][k] + bias[n], bf16 in/out, f32 accum.
// 128x128 tile, 4 waves (2x2 of 64x64), BK=32, global_load_lds staging.
__global__ __launch_bounds__(256, 2)
void gemm_bt(const u16* __restrict__ A, const u16* __restrict__ Bt,
             const float* __restrict__ bias, u16* __restrict__ Y, int Kp) {
    __shared__ u16 a_tile[128 * 32];
    __shared__ u16 b_tile[128 * 32];
    const int tid = threadIdx.x;
    const int w = tid >> 6, l = tid & 63;
    const int brow = blockIdx.y << 7, bcol = blockIdx.x << 7;
    const int wr = (w >> 1) << 6, wc = (w & 1) << 6;
    const int lr = l & 15, lk = (l >> 4) << 3;

    // staging geometry: per issue, wave w covers 16 rows, lane l -> row +l/4, col (l%4)*8
    const int ra0 = (w << 4) + (l >> 2);
    const int kc  = (l & 3) << 3;
    const u16* ga = A  + (size_t)(brow + ra0) * Kp + kc;
    const u16* gb = Bt + (size_t)(bcol + ra0) * Kp + kc;
    u16* la = a_tile + (w << 4) * 32;
    u16* lb = b_tile + (w << 4) * 32;

    f32x4 acc[4][4] = {};

    for (int kk = 0; kk < Kp; kk += 32) {
        gload_lds16(ga + kk,                    la);
        gload_lds16(ga + kk + (size_t)64 * Kp,  la + 64 * 32);
        gload_lds16(gb + kk,                    lb);
        gload_lds16(gb + kk + (size_t)64 * Kp,  lb + 64 * 32);
        __syncthreads();

        bf16x8 af[4], bfr[4];
        #pragma unroll
        for (int mi = 0; mi < 4; ++mi)
            af[mi] = *reinterpret_cast<const bf16x8*>(&a_tile[(wr + mi * 16 + lr) * 32 + lk]);
        #pragma unroll
        for (int ni = 0; ni < 4; ++ni)
            bfr[ni] = *reinterpret_cast<const bf16x8*>(&b_tile[(wc + ni * 16 + lr) * 32 + lk]);
        #pragma unroll
        for (int mi = 0; mi < 4; ++mi)
            #pragma unroll
            for (int ni = 0; ni < 4; ++ni)
                acc[mi][ni] = __builtin_amdgcn_mfma_f32_16x16x32_bf16(af[mi], bfr[ni], acc[mi][ni], 0, 0, 0);
        __syncthreads();
    }

    const int row0 = (l >> 4) << 2;
    #pragma unroll
    for (int ni = 0; ni < 4; ++ni) {
        const int gc = bcol + wc + ni * 16 + lr;
        const float bv = bias[gc];
        #pragma unroll
        for (int mi = 0; mi < 4; ++mi) {
            #pragma unroll
            for (int j = 0; j < 4; ++j) {
                const int gr = brow + wr + mi * 16 + row0 + j;
                Y[(size_t)gr * N_ + gc] = f2bf(acc[mi][ni][j] + bv);
            }
        }
    }
}

// sequential forget-mult scan; one thread per (b, h) channel.
// layer==0: write bf16 x2; layer==1: write f32 x to d_out. hout: last cell state.
__global__ void scan_kernel(const u16* __restrict__ y, void* __restrict__ xout,
                            float* __restrict__ hout, int layer) {
    const int b = blockIdx.x >> 2;
    const int h = ((blockIdx.x & 3) << 8) + threadIdx.x;
    const u16* yb = y + (size_t)b * T_ * N_;
    u16*   xo_bf = (u16*)xout;
    float* xo_f  = (float*)xout;
    float c = 0.f;
    #pragma unroll 8
    for (int t = 0; t < T_; ++t) {
        const int base = t * N_;
        const float Z = bf2f(yb[base + h]);
        const float F = bf2f(yb[base + H_ + h]);
        const float O = bf2f(yb[base + 2 * H_ + h]);
        const float f = 1.f / (1.f + __expf(-F));
        const float z = fmaxf(Z, 0.f);
        c = f * z + (1.f - f) * c;
        const float o = 1.f / (1.f + __expf(-O));
        const float outv = o * c;
        const size_t oi = ((size_t)b * T_ + t) * H_ + h;
        if (layer) xo_f[oi] = outv; else xo_bf[oi] = f2bf(outv);
    }
    hout[(size_t)(((b << 1) + layer) << 10) + h] = c;
}

extern "C" void kernel_launch(void* const* d_in, const int* in_sizes, int n_in,
                              void* d_out, int out_size, void* d_ws, size_t ws_size,
                              hipStream_t stream) {
    const float* pa = (const float*)d_in[0];
    const float* st = (const float*)d_in[1];
    const float* md = (const float*)d_in[2];
    const float* W1 = (const float*)d_in[3];
    const float* b1 = (const float*)d_in[4];
    const float* W2 = (const float*)d_in[5];
    const float* b2 = (const float*)d_in[6];
    float* out = (float*)d_out;

    char* ws = (char*)d_ws;
    u16* y  = (u16*)ws;                                                // [16384][3072] bf16
    u16* x  = (u16*)(ws + (size_t)M_ * N_ * 2);                        // [16384][1600] bf16
    u16* Wt = (u16*)(ws + (size_t)M_ * N_ * 2 + (size_t)M_ * 1600 * 2); // [3072][1600] bf16

    // ---- layer 1 ----
    concat_cast<<<M_, 256, 0, stream>>>(pa, st, md, x);
    wtrans<<<dim3(N_ / 32, 50), 256, 0, stream>>>(W1, Wt, 1591, 1600);
    gemm_bt<<<dim3(N_ / 128, M_ / 128), 256, 0, stream>>>(x, Wt, b1, y, 1600);
    scan_kernel<<<32, 256, 0, stream>>>(y, x, out + (size_t)M_ * H_, 0);  // x2 bf16 into x

    // ---- layer 2 ----
    wtrans<<<dim3(N_ / 32, 32), 256, 0, stream>>>(W2, Wt, 1024, 1024);
    gemm_bt<<<dim3(N_ / 128, M_ / 128), 256, 0, stream>>>(x, Wt, b2, y, 1024);
    scan_kernel<<<32, 256, 0, stream>>>(y, out, out + (size_t)M_ * H_, 1);
}

// Round 2
// 480.264 us; speedup vs baseline: 4.1620x; 4.1620x over previous
//
#include <hip/hip_runtime.h>

typedef unsigned short u16;
typedef unsigned int   u32;
typedef __attribute__((ext_vector_type(8))) short bf16x8;
typedef __attribute__((ext_vector_type(4))) float f32x4;

#define B_ 8
#define T_ 2048
#define M_ 16384          // B*T
#define N_ 3072           // 3*H
#define H_ 1024
#define L_ 64             // scan chunk length
#define NC_ 32            // chunks per sequence (T_/L_)

__device__ __forceinline__ u16 f2bf(float f) {
    union { float f; unsigned u; } v; v.f = f;
    unsigned r = v.u + 0x7FFFu + ((v.u >> 16) & 1u);   // RNE
    return (u16)(r >> 16);
}
__device__ __forceinline__ float bf2f(u16 s) {
    union { unsigned u; float f; } v; v.u = ((unsigned)s) << 16;
    return v.f;
}
__device__ __forceinline__ float sigm(float x) {
    return 1.f / (1.f + __expf(-x));
}

__device__ __forceinline__ void gload_lds16(const void* g, void* l) {
    __builtin_amdgcn_global_load_lds(
        (const __attribute__((address_space(1))) unsigned int*)g,
        (__attribute__((address_space(3))) unsigned int*)l,
        16, 0, 0);
}

// Build bf16 x1 [16384][1600] = concat(pa, st, md) zero-padded 1591..1600
__global__ void concat_cast(const float* __restrict__ pa, const float* __restrict__ st,
                            const float* __restrict__ md, u16* __restrict__ x) {
    const int m = blockIdx.x;
    const float* pam = pa + (size_t)m * 695;
    const float* stm = st + (size_t)m * 812;
    const float* mdm = md + (size_t)m * 84;
    u16* xm = x + (size_t)m * 1600;
    for (int d = threadIdx.x; d < 1600; d += 256) {
        float v;
        if (d < 695)       v = pam[d];
        else if (d < 1507) v = stm[d - 695];
        else if (d < 1591) v = mdm[d - 1507];
        else               v = 0.f;
        xm[d] = f2bf(v);
    }
}

// Wt[n][k] = bf16(W[k][n]), K rows valid, zero-pad to Kp
__global__ void wtrans(const float* __restrict__ W, u16* __restrict__ Wt, int K, int Kp) {
    __shared__ float tile[32][33];
    const int n0 = blockIdx.x << 5;
    const int k0 = blockIdx.y << 5;
    const int tx = threadIdx.x & 31, ty = threadIdx.x >> 5;   // 32 x 8
    #pragma unroll
    for (int i = 0; i < 32; i += 8) {
        int k = k0 + ty + i;
        tile[ty + i][tx] = (k < K) ? W[(size_t)k * N_ + n0 + tx] : 0.f;
    }
    __syncthreads();
    #pragma unroll
    for (int i = 0; i < 32; i += 8) {
        int n = n0 + ty + i;
        Wt[(size_t)n * Kp + k0 + tx] = f2bf(tile[tx][ty + i]);
    }
}

// C[m][n] = sum_k A[m][k]*Bt[n][k] + bias[n], bf16 in/out, f32 accum.
// 128x128 tile, 4 waves (2x2 of 64x64), BK=32, global_load_lds staging.
__global__ __launch_bounds__(256, 2)
void gemm_bt(const u16* __restrict__ A, const u16* __restrict__ Bt,
             const float* __restrict__ bias, u16* __restrict__ Y, int Kp) {
    __shared__ u16 a_tile[128 * 32];
    __shared__ u16 b_tile[128 * 32];
    const int tid = threadIdx.x;
    const int w = tid >> 6, l = tid & 63;
    const int brow = blockIdx.y << 7, bcol = blockIdx.x << 7;
    const int wr = (w >> 1) << 6, wc = (w & 1) << 6;
    const int lr = l & 15, lk = (l >> 4) << 3;

    const int ra0 = (w << 4) + (l >> 2);
    const int kc  = (l & 3) << 3;
    const u16* ga = A  + (size_t)(brow + ra0) * Kp + kc;
    const u16* gb = Bt + (size_t)(bcol + ra0) * Kp + kc;
    u16* la = a_tile + (w << 4) * 32;
    u16* lb = b_tile + (w << 4) * 32;

    f32x4 acc[4][4] = {};

    for (int kk = 0; kk < Kp; kk += 32) {
        gload_lds16(ga + kk,                    la);
        gload_lds16(ga + kk + (size_t)64 * Kp,  la + 64 * 32);
        gload_lds16(gb + kk,                    lb);
        gload_lds16(gb + kk + (size_t)64 * Kp,  lb + 64 * 32);
        __syncthreads();

        bf16x8 af[4], bfr[4];
        #pragma unroll
        for (int mi = 0; mi < 4; ++mi)
            af[mi] = *reinterpret_cast<const bf16x8*>(&a_tile[(wr + mi * 16 + lr) * 32 + lk]);
        #pragma unroll
        for (int ni = 0; ni < 4; ++ni)
            bfr[ni] = *reinterpret_cast<const bf16x8*>(&b_tile[(wc + ni * 16 + lr) * 32 + lk]);
        #pragma unroll
        for (int mi = 0; mi < 4; ++mi)
            #pragma unroll
            for (int ni = 0; ni < 4; ++ni)
                acc[mi][ni] = __builtin_amdgcn_mfma_f32_16x16x32_bf16(af[mi], bfr[ni], acc[mi][ni], 0, 0, 0);
        __syncthreads();
    }

    const int row0 = (l >> 4) << 2;
    #pragma unroll
    for (int ni = 0; ni < 4; ++ni) {
        const int gc = bcol + wc + ni * 16 + lr;
        const float bv = bias[gc];
        #pragma unroll
        for (int mi = 0; mi < 4; ++mi) {
            #pragma unroll
            for (int j = 0; j < 4; ++j) {
                const int gr = brow + wr + mi * 16 + row0 + j;
                Y[(size_t)gr * N_ + gc] = f2bf(acc[mi][ni][j] + bv);
            }
        }
    }
}

// ---- chunked scan ----
// Phase 1: per (b, chunk, h-pair): local scan with c_in = 0, collect affine map
// (aprod = prod(1-f), cend = local c at chunk end). Reads only Z,F gates.
// grid: b*(NC_*2) + chunk*2 + hb   blocks of 256 threads, 2 h per thread.
__global__ void scan_p1(const u16* __restrict__ y, float* __restrict__ aprod,
                        float* __restrict__ cend) {
    const int hb = blockIdx.x & 1;
    const int chunk = (blockIdx.x >> 1) & (NC_ - 1);
    const int b = blockIdx.x >> 6;
    const int h = (hb << 9) + (threadIdx.x << 1);
    const u16* yb = y + ((size_t)b * T_ + (size_t)chunk * L_) * N_;
    float a0 = 1.f, a1 = 1.f, c0 = 0.f, c1 = 0.f;
    #pragma unroll 4
    for (int t = 0; t < L_; ++t) {
        const u32 zz = *reinterpret_cast<const u32*>(&yb[t * N_ + h]);
        const u32 ff = *reinterpret_cast<const u32*>(&yb[t * N_ + H_ + h]);
        const float f0 = sigm(bf2f((u16)ff));
        const float f1 = sigm(bf2f((u16)(ff >> 16)));
        const float z0 = fmaxf(bf2f((u16)zz), 0.f);
        const float z1 = fmaxf(bf2f((u16)(zz >> 16)), 0.f);
        c0 = f0 * z0 + (1.f - f0) * c0;  a0 *= (1.f - f0);
        c1 = f1 * z1 + (1.f - f1) * c1;  a1 *= (1.f - f1);
    }
    const size_t idx = ((size_t)b * NC_ + chunk) * H_ + h;
    *reinterpret_cast<float2*>(&aprod[idx]) = make_float2(a0, a1);
    *reinterpret_cast<float2*>(&cend[idx])  = make_float2(c0, c1);
}

// Phase 2: tiny sequential scan over chunks; cin[b][chunk][h] = incoming c.
// Also writes final cell state to hout. grid: 32 blocks x 256.
__global__ void scan_p2(const float* __restrict__ aprod, const float* __restrict__ cend,
                        float* __restrict__ cin, float* __restrict__ hout, int layer) {
    const int b = blockIdx.x >> 2;
    const int h = ((blockIdx.x & 3) << 8) + threadIdx.x;
    float c = 0.f;
    #pragma unroll
    for (int k = 0; k < NC_; ++k) {
        const size_t idx = ((size_t)b * NC_ + k) * H_ + h;
        cin[idx] = c;
        c = aprod[idx] * c + cend[idx];
    }
    hout[(size_t)(((b << 1) + layer) << 10) + h] = c;
}

// Phase 3: redo local scan seeded with cin, apply output gate, store.
// layer==0: bf16 into x; layer==1: f32 into d_out.
__global__ void scan_p3(const u16* __restrict__ y, const float* __restrict__ cin,
                        void* __restrict__ xout, int layer) {
    const int hb = blockIdx.x & 1;
    const int chunk = (blockIdx.x >> 1) & (NC_ - 1);
    const int b = blockIdx.x >> 6;
    const int h = (hb << 9) + (threadIdx.x << 1);
    const u16* yb = y + ((size_t)b * T_ + (size_t)chunk * L_) * N_;
    const size_t cidx = ((size_t)b * NC_ + chunk) * H_ + h;
    const float2 cv = *reinterpret_cast<const float2*>(&cin[cidx]);
    float c0 = cv.x, c1 = cv.y;
    u32*    xo_bf = (u32*)xout;
    float2* xo_f  = (float2*)xout;
    const size_t obase = ((size_t)b * T_ + (size_t)chunk * L_) * H_ + h;
    #pragma unroll 4
    for (int t = 0; t < L_; ++t) {
        const u32 zz = *reinterpret_cast<const u32*>(&yb[t * N_ + h]);
        const u32 ff = *reinterpret_cast<const u32*>(&yb[t * N_ + H_ + h]);
        const u32 oo = *reinterpret_cast<const u32*>(&yb[t * N_ + 2 * H_ + h]);
        const float f0 = sigm(bf2f((u16)ff));
        const float f1 = sigm(bf2f((u16)(ff >> 16)));
        const float z0 = fmaxf(bf2f((u16)zz), 0.f);
        const float z1 = fmaxf(bf2f((u16)(zz >> 16)), 0.f);
        c0 = f0 * z0 + (1.f - f0) * c0;
        c1 = f1 * z1 + (1.f - f1) * c1;
        const float o0 = sigm(bf2f((u16)oo)) * c0;
        const float o1 = sigm(bf2f((u16)(oo >> 16))) * c1;
        const size_t oi = obase + (size_t)t * H_;
        if (layer) xo_f[oi >> 1] = make_float2(o0, o1);
        else       xo_bf[oi >> 1] = (u32)f2bf(o0) | ((u32)f2bf(o1) << 16);
    }
}

extern "C" void kernel_launch(void* const* d_in, const int* in_sizes, int n_in,
                              void* d_out, int out_size, void* d_ws, size_t ws_size,
                              hipStream_t stream) {
    const float* pa = (const float*)d_in[0];
    const float* st = (const float*)d_in[1];
    const float* md = (const float*)d_in[2];
    const float* W1 = (const float*)d_in[3];
    const float* b1 = (const float*)d_in[4];
    const float* W2 = (const float*)d_in[5];
    const float* b2 = (const float*)d_in[6];
    float* out = (float*)d_out;

    char* ws = (char*)d_ws;
    const size_t y_bytes = (size_t)M_ * N_ * 2;          // 100.7 MB
    const size_t x_bytes = (size_t)M_ * 1600 * 2;        // 52.4 MB
    u16* y  = (u16*)ws;
    u16* x  = (u16*)(ws + y_bytes);
    u16* Wt = (u16*)(ws + y_bytes + x_bytes);            // 9.8 MB
    // scan scratch lives in the tail of the x buffer (x output only uses 33.5MB)
    char* scr = ws + y_bytes + (size_t)M_ * H_ * 2;
    const size_t sarr = (size_t)B_ * NC_ * H_ * 4;       // 1 MB each
    float* aprod = (float*)scr;
    float* cend  = (float*)(scr + sarr);
    float* cin   = (float*)(scr + 2 * sarr);

    float* hout = out + (size_t)M_ * H_;

    // ---- layer 1 ----
    concat_cast<<<M_, 256, 0, stream>>>(pa, st, md, x);
    wtrans<<<dim3(N_ / 32, 50), 256, 0, stream>>>(W1, Wt, 1591, 1600);
    gemm_bt<<<dim3(N_ / 128, M_ / 128), 256, 0, stream>>>(x, Wt, b1, y, 1600);
    scan_p1<<<B_ * NC_ * 2, 256, 0, stream>>>(y, aprod, cend);
    scan_p2<<<32, 256, 0, stream>>>(aprod, cend, cin, hout, 0);
    scan_p3<<<B_ * NC_ * 2, 256, 0, stream>>>(y, cin, x, 0);   // bf16 x2 into x

    // ---- layer 2 ----
    wtrans<<<dim3(N_ / 32, 32), 256, 0, stream>>>(W2, Wt, 1024, 1024);
    gemm_bt<<<dim3(N_ / 128, M_ / 128), 256, 0, stream>>>(x, Wt, b2, y, 1024);
    scan_p1<<<B_ * NC_ * 2, 256, 0, stream>>>(y, aprod, cend);
    scan_p2<<<32, 256, 0, stream>>>(aprod, cend, cin, hout, 1);
    scan_p3<<<B_ * NC_ * 2, 256, 0, stream>>>(y, cin, out, 1);
}

// Round 3
// 455.115 us; speedup vs baseline: 4.3920x; 1.0553x over previous
//
#include <hip/hip_runtime.h>

typedef unsigned short u16;
typedef unsigned int   u32;
typedef __attribute__((ext_vector_type(8))) short bf16x8;
typedef __attribute__((ext_vector_type(4))) float f32x4;

#define B_ 8
#define T_ 2048
#define M_ 16384          // B*T
#define N_ 3072           // 3*H
#define H_ 1024
#define L_ 64             // scan chunk length
#define NC_ 32            // chunks per sequence (T_/L_)

__device__ __forceinline__ u16 f2bf(float f) {
    union { float f; unsigned u; } v; v.f = f;
    unsigned r = v.u + 0x7FFFu + ((v.u >> 16) & 1u);   // RNE
    return (u16)(r >> 16);
}
__device__ __forceinline__ float bf2f(u16 s) {
    union { unsigned u; float f; } v; v.u = ((unsigned)s) << 16;
    return v.f;
}
__device__ __forceinline__ float sigm(float x) {
    return 1.f / (1.f + __expf(-x));
}

__device__ __forceinline__ void gload_lds16(const void* g, void* l) {
    __builtin_amdgcn_global_load_lds(
        (const __attribute__((address_space(1))) unsigned int*)g,
        (__attribute__((address_space(3))) unsigned int*)l,
        16, 0, 0);
}

// Build bf16 x1 [16384][1600] = concat(pa, st, md) zero-padded 1591..1600
__global__ void concat_cast(const float* __restrict__ pa, const float* __restrict__ st,
                            const float* __restrict__ md, u16* __restrict__ x) {
    const int m = blockIdx.x;
    const float* pam = pa + (size_t)m * 695;
    const float* stm = st + (size_t)m * 812;
    const float* mdm = md + (size_t)m * 84;
    u16* xm = x + (size_t)m * 1600;
    for (int d = threadIdx.x; d < 1600; d += 256) {
        float v;
        if (d < 695)       v = pam[d];
        else if (d < 1507) v = stm[d - 695];
        else if (d < 1591) v = mdm[d - 1507];
        else               v = 0.f;
        xm[d] = f2bf(v);
    }
}

// Wt[n][k] = bf16(W[k][n]), K rows valid, zero-pad to Kp
__global__ void wtrans(const float* __restrict__ W, u16* __restrict__ Wt, int K, int Kp) {
    __shared__ float tile[32][33];
    const int n0 = blockIdx.x << 5;
    const int k0 = blockIdx.y << 5;
    const int tx = threadIdx.x & 31, ty = threadIdx.x >> 5;   // 32 x 8
    #pragma unroll
    for (int i = 0; i < 32; i += 8) {
        int k = k0 + ty + i;
        tile[ty + i][tx] = (k < K) ? W[(size_t)k * N_ + n0 + tx] : 0.f;
    }
    __syncthreads();
    #pragma unroll
    for (int i = 0; i < 32; i += 8) {
        int n = n0 + ty + i;
        Wt[(size_t)n * Kp + k0 + tx] = f2bf(tile[tx][ty + i]);
    }
}

// ---- 256x256 8-phase GEMM, BK=64 (2 K-halves of 32), 8 waves (2m x 4n) ----
// C[m][n] = sum_k A[m][k]*Bt[n][k] + bias[n].  LDS ring: 2 K-tile buffers,
// regions [buf][A/B][kh] of [256 rows][32 k] u16 (16KB each), 128KB total.
// 16B k-slots XOR-swizzled with (row&3); applied on the global SOURCE address
// at stage time (LDS write stays linear for global_load_lds) and on the
// ds_read address.  vmcnt(4) only at phases 2/4 of each K-tile (counted, no drain).
#define AO_(c, kh) ((((c) << 2) + (kh)) << 13)
#define BO_(c, kh) ((((c) << 2) + 2 + (kh)) << 13)

__global__ __launch_bounds__(512, 1)
void gemm8p(const u16* __restrict__ A, const u16* __restrict__ Bt,
            const float* __restrict__ bias, u16* __restrict__ Y,
            int Kp, int NK, int NBN) {
    __shared__ u16 lds[65536];   // 128 KB
    const int tid = threadIdx.x;
    const int w = tid >> 6, l = tid & 63;
    const int wm = w >> 2, wn = w & 3;

    // XCD-bijective swizzle (gridDim.x % 8 == 0)
    const int cpx = gridDim.x >> 3;
    const int xg = (blockIdx.x & 7) * cpx + (blockIdx.x >> 3);
    const int bm = xg / NBN, bn = xg % NBN;
    const int brow = bm << 8, bcol = bn << 8;

    // staging lane geometry: 1KB per wave-issue = 16 rows x 64B; lane l ->
    // row +(l>>2), lds 16B-slot (l&3); inverse-swizzled global slot:
    const int srow = l >> 2;
    const int gslot = (l & 3) ^ (srow & 3);
    const u16* ga = A  + (size_t)(brow + w * 32 + srow) * Kp + gslot * 8;
    const u16* gb = Bt + (size_t)(bcol + w * 32 + srow) * Kp + gslot * 8;
    const int ldst = w << 10;    // u16 offset of this wave's first 1KB chunk

    // frag-read lane constant: row part (l&15)*32, swizzled slot ((l>>4)^(l&3))*8
    const int fl = ((l & 15) << 5) + ((((l >> 4) ^ (l & 3)) & 3) << 3);
    const int abase0 = (wm << 7) << 5;          // wm*128 rows * 32
    const int bbase0 = (wn << 6) << 5;          // wn*64 rows * 32

#define STG(OFF, gp, kt, kh) do {                                              \
    gload_lds16((gp) + (size_t)(kt) * 64 + (kh) * 32, &lds[(OFF) + ldst]);     \
    gload_lds16((gp) + 16 * (size_t)Kp + (size_t)(kt) * 64 + (kh) * 32,        \
                &lds[(OFF) + ldst + 512]);                                     \
} while (0)

    f32x4 acc[8][4] = {};
    bf16x8 bfr[4];

    // prologue: K-tile 0 (all 4 halves) + K-tile 1 kh0 halves
    STG(AO_(0, 0), ga, 0, 0); STG(BO_(0, 0), gb, 0, 0);
    STG(AO_(0, 1), ga, 0, 1); STG(BO_(0, 1), gb, 0, 1);
    STG(AO_(1, 0), ga, 1, 0); STG(BO_(1, 0), gb, 1, 0);
    asm volatile("s_waitcnt vmcnt(4)" ::: "memory");
    __builtin_amdgcn_s_barrier();
    asm volatile("" ::: "memory");

#define PHASE(CH, KH, LOADB, STAGECODE, VMW) do {                              \
    bf16x8 af[4];                                                              \
    { const int ab = AO_(cur, KH) + abase0 + ((CH) << 11);                     \
      _Pragma("unroll")                                                        \
      for (int mf = 0; mf < 4; ++mf)                                           \
          af[mf] = *reinterpret_cast<const bf16x8*>(&lds[ab + (mf << 9) + fl]);\
    }                                                                          \
    if (LOADB) {                                                               \
        const int bb = BO_(cur, KH) + bbase0;                                  \
        _Pragma("unroll")                                                      \
        for (int nf = 0; nf < 4; ++nf)                                         \
            bfr[nf] = *reinterpret_cast<const bf16x8*>(&lds[bb + (nf << 9) + fl]); \
    }                                                                          \
    STAGECODE;                                                                 \
    if (VMW) asm volatile("s_waitcnt vmcnt(4)" ::: "memory");                  \
    asm volatile("" ::: "memory");                                             \
    __builtin_amdgcn_s_barrier();                                              \
    asm volatile("s_waitcnt lgkmcnt(0)" ::: "memory");                         \
    __builtin_amdgcn_sched_barrier(0);                                         \
    __builtin_amdgcn_s_setprio(1);                                             \
    _Pragma("unroll")                                                          \
    for (int mf = 0; mf < 4; ++mf)                                             \
        _Pragma("unroll")                                                      \
        for (int nf = 0; nf < 4; ++nf)                                         \
            acc[(CH) * 4 + mf][nf] = __builtin_amdgcn_mfma_f32_16x16x32_bf16(  \
                af[mf], bfr[nf], acc[(CH) * 4 + mf][nf], 0, 0, 0);             \
    __builtin_amdgcn_s_setprio(0);                                             \
    __builtin_amdgcn_sched_barrier(0);                                         \
    __builtin_amdgcn_s_barrier();                                              \
    asm volatile("" ::: "memory");                                             \
} while (0)

    for (int kt = 0; kt < NK; ++kt) {
        const int cur = kt & 1;
        const int kn1 = (kt + 1 < NK) ? kt + 1 : kt;   // source clamp (dest region is dead)
        const int kn2 = (kt + 2 < NK) ? kt + 2 : kt;
        PHASE(0, 0, 1, { STG(AO_(cur ^ 1, 1), ga, kn1, 1); }, 0);
        PHASE(1, 0, 0, { STG(BO_(cur ^ 1, 1), gb, kn1, 1); }, 1);
        PHASE(0, 1, 1, { STG(AO_(cur, 0),     ga, kn2, 0); }, 0);
        PHASE(1, 1, 0, { STG(BO_(cur, 0),     gb, kn2, 0); }, 1);
    }

    asm volatile("s_waitcnt vmcnt(0)" ::: "memory");   // drain tail stages

    // epilogue: C/D layout col=lane&15, row=(lane>>4)*4+j
    const int crow0 = brow + wm * 128 + ((l >> 4) << 2);
    const int ccol0 = bcol + wn * 64 + (l & 15);
    #pragma unroll
    for (int nf = 0; nf < 4; ++nf) {
        const int gc = ccol0 + nf * 16;
        const float bv = bias[gc];
        #pragma unroll
        for (int mfi = 0; mfi < 8; ++mfi) {
            #pragma unroll
            for (int j = 0; j < 4; ++j)
                Y[(size_t)(crow0 + mfi * 16 + j) * N_ + gc] = f2bf(acc[mfi][nf][j] + bv);
        }
    }
#undef PHASE
#undef STG
}

// ---- chunked scan ----
__global__ void scan_p1(const u16* __restrict__ y, float* __restrict__ aprod,
                        float* __restrict__ cend) {
    const int hb = blockIdx.x & 1;
    const int chunk = (blockIdx.x >> 1) & (NC_ - 1);
    const int b = blockIdx.x >> 6;
    const int h = (hb << 9) + (threadIdx.x << 1);
    const u16* yb = y + ((size_t)b * T_ + (size_t)chunk * L_) * N_;
    float a0 = 1.f, a1 = 1.f, c0 = 0.f, c1 = 0.f;
    #pragma unroll 4
    for (int t = 0; t < L_; ++t) {
        const u32 zz = *reinterpret_cast<const u32*>(&yb[t * N_ + h]);
        const u32 ff = *reinterpret_cast<const u32*>(&yb[t * N_ + H_ + h]);
        const float f0 = sigm(bf2f((u16)ff));
        const float f1 = sigm(bf2f((u16)(ff >> 16)));
        const float z0 = fmaxf(bf2f((u16)zz), 0.f);
        const float z1 = fmaxf(bf2f((u16)(zz >> 16)), 0.f);
        c0 = f0 * z0 + (1.f - f0) * c0;  a0 *= (1.f - f0);
        c1 = f1 * z1 + (1.f - f1) * c1;  a1 *= (1.f - f1);
    }
    const size_t idx = ((size_t)b * NC_ + chunk) * H_ + h;
    *reinterpret_cast<float2*>(&aprod[idx]) = make_float2(a0, a1);
    *reinterpret_cast<float2*>(&cend[idx])  = make_float2(c0, c1);
}

__global__ void scan_p2(const float* __restrict__ aprod, const float* __restrict__ cend,
                        float* __restrict__ cin, float* __restrict__ hout, int layer) {
    const int b = blockIdx.x >> 2;
    const int h = ((blockIdx.x & 3) << 8) + threadIdx.x;
    float c = 0.f;
    #pragma unroll
    for (int k = 0; k < NC_; ++k) {
        const size_t idx = ((size_t)b * NC_ + k) * H_ + h;
        cin[idx] = c;
        c = aprod[idx] * c + cend[idx];
    }
    hout[(size_t)(((b << 1) + layer) << 10) + h] = c;
}

__global__ void scan_p3(const u16* __restrict__ y, const float* __restrict__ cin,
                        void* __restrict__ xout, int layer) {
    const int hb = blockIdx.x & 1;
    const int chunk = (blockIdx.x >> 1) & (NC_ - 1);
    const int b = blockIdx.x >> 6;
    const int h = (hb << 9) + (threadIdx.x << 1);
    const u16* yb = y + ((size_t)b * T_ + (size_t)chunk * L_) * N_;
    const size_t cidx = ((size_t)b * NC_ + chunk) * H_ + h;
    const float2 cv = *reinterpret_cast<const float2*>(&cin[cidx]);
    float c0 = cv.x, c1 = cv.y;
    u32*    xo_bf = (u32*)xout;
    float2* xo_f  = (float2*)xout;
    const size_t obase = ((size_t)b * T_ + (size_t)chunk * L_) * H_ + h;
    #pragma unroll 4
    for (int t = 0; t < L_; ++t) {
        const u32 zz = *reinterpret_cast<const u32*>(&yb[t * N_ + h]);
        const u32 ff = *reinterpret_cast<const u32*>(&yb[t * N_ + H_ + h]);
        const u32 oo = *reinterpret_cast<const u32*>(&yb[t * N_ + 2 * H_ + h]);
        const float f0 = sigm(bf2f((u16)ff));
        const float f1 = sigm(bf2f((u16)(ff >> 16)));
        const float z0 = fmaxf(bf2f((u16)zz), 0.f);
        const float z1 = fmaxf(bf2f((u16)(zz >> 16)), 0.f);
        c0 = f0 * z0 + (1.f - f0) * c0;
        c1 = f1 * z1 + (1.f - f1) * c1;
        const float o0 = sigm(bf2f((u16)oo)) * c0;
        const float o1 = sigm(bf2f((u16)(oo >> 16))) * c1;
        const size_t oi = obase + (size_t)t * H_;
        if (layer) xo_f[oi >> 1] = make_float2(o0, o1);
        else       xo_bf[oi >> 1] = (u32)f2bf(o0) | ((u32)f2bf(o1) << 16);
    }
}

extern "C" void kernel_launch(void* const* d_in, const int* in_sizes, int n_in,
                              void* d_out, int out_size, void* d_ws, size_t ws_size,
                              hipStream_t stream) {
    const float* pa = (const float*)d_in[0];
    const float* st = (const float*)d_in[1];
    const float* md = (const float*)d_in[2];
    const float* W1 = (const float*)d_in[3];
    const float* b1 = (const float*)d_in[4];
    const float* W2 = (const float*)d_in[5];
    const float* b2 = (const float*)d_in[6];
    float* out = (float*)d_out;

    char* ws = (char*)d_ws;
    const size_t y_bytes = (size_t)M_ * N_ * 2;          // 100.7 MB
    const size_t x_bytes = (size_t)M_ * 1600 * 2;        // 52.4 MB
    u16* y  = (u16*)ws;
    u16* x  = (u16*)(ws + y_bytes);
    u16* Wt = (u16*)(ws + y_bytes + x_bytes);            // 9.8 MB
    char* scr = ws + y_bytes + (size_t)M_ * H_ * 2;
    const size_t sarr = (size_t)B_ * NC_ * H_ * 4;       // 1 MB each
    float* aprod = (float*)scr;
    float* cend  = (float*)(scr + sarr);
    float* cin   = (float*)(scr + 2 * sarr);

    float* hout = out + (size_t)M_ * H_;

    const int grid_g = (M_ / 256) * (N_ / 256);          // 64*12 = 768 (%8==0)

    // ---- layer 1 ----
    concat_cast<<<M_, 256, 0, stream>>>(pa, st, md, x);
    wtrans<<<dim3(N_ / 32, 50), 256, 0, stream>>>(W1, Wt, 1591, 1600);
    gemm8p<<<grid_g, 512, 0, stream>>>(x, Wt, b1, y, 1600, 25, N_ / 256);
    scan_p1<<<B_ * NC_ * 2, 256, 0, stream>>>(y, aprod, cend);
    scan_p2<<<32, 256, 0, stream>>>(aprod, cend, cin, hout, 0);
    scan_p3<<<B_ * NC_ * 2, 256, 0, stream>>>(y, cin, x, 0);   // bf16 x2 into x

    // ---- layer 2 ----
    wtrans<<<dim3(N_ / 32, 32), 256, 0, stream>>>(W2, Wt, 1024, 1024);
    gemm8p<<<grid_g, 512, 0, stream>>>(x, Wt, b2, y, 1024, 16, N_ / 256);
    scan_p1<<<B_ * NC_ * 2, 256, 0, stream>>>(y, aprod, cend);
    scan_p2<<<32, 256, 0, stream>>>(aprod, cend, cin, hout, 1);
    scan_p3<<<B_ * NC_ * 2, 256, 0, stream>>>(y, cin, out, 1);
}

// Round 4
// 451.390 us; speedup vs baseline: 4.4283x; 1.0083x over previous
//
#include <hip/hip_runtime.h>

typedef unsigned short u16;
typedef unsigned int   u32;
typedef __attribute__((ext_vector_type(8))) short bf16x8;
typedef __attribute__((ext_vector_type(4))) float f32x4;
typedef __attribute__((ext_vector_type(2))) unsigned int u32x2;

#define B_ 8
#define T_ 2048
#define M_ 16384          // B*T
#define N_ 3072           // 3*H
#define H_ 1024
#define L_ 64             // scan chunk length
#define NC_ 32            // chunks per sequence (T_/L_)

__device__ __forceinline__ u16 f2bf(float f) {
    union { float f; unsigned u; } v; v.f = f;
    unsigned r = v.u + 0x7FFFu + ((v.u >> 16) & 1u);   // RNE
    return (u16)(r >> 16);
}
__device__ __forceinline__ float bf2f(u16 s) {
    union { unsigned u; float f; } v; v.u = ((unsigned)s) << 16;
    return v.f;
}
__device__ __forceinline__ float sigm(float x) {
    return 1.f / (1.f + __expf(-x));
}

__device__ __forceinline__ void gload_lds16(const void* g, void* l) {
    __builtin_amdgcn_global_load_lds(
        (const __attribute__((address_space(1))) unsigned int*)g,
        (__attribute__((address_space(3))) unsigned int*)l,
        16, 0, 0);
}

// Build bf16 x1 [16384][1600] = concat(pa, st, md) zero-padded 1591..1600
__global__ void concat_cast(const float* __restrict__ pa, const float* __restrict__ st,
                            const float* __restrict__ md, u16* __restrict__ x) {
    const int m = blockIdx.x;
    const float* pam = pa + (size_t)m * 695;
    const float* stm = st + (size_t)m * 812;
    const float* mdm = md + (size_t)m * 84;
    u16* xm = x + (size_t)m * 1600;
    for (int d = threadIdx.x; d < 1600; d += 256) {
        float v;
        if (d < 695)       v = pam[d];
        else if (d < 1507) v = stm[d - 695];
        else if (d < 1591) v = mdm[d - 1507];
        else               v = 0.f;
        xm[d] = f2bf(v);
    }
}

// Wt[n][k] = bf16(W[k][n]), K rows valid, zero-pad to Kp
__global__ void wtrans(const float* __restrict__ W, u16* __restrict__ Wt, int K, int Kp) {
    __shared__ float tile[32][33];
    const int n0 = blockIdx.x << 5;
    const int k0 = blockIdx.y << 5;
    const int tx = threadIdx.x & 31, ty = threadIdx.x >> 5;   // 32 x 8
    #pragma unroll
    for (int i = 0; i < 32; i += 8) {
        int k = k0 + ty + i;
        tile[ty + i][tx] = (k < K) ? W[(size_t)k * N_ + n0 + tx] : 0.f;
    }
    __syncthreads();
    #pragma unroll
    for (int i = 0; i < 32; i += 8) {
        int n = n0 + ty + i;
        Wt[(size_t)n * Kp + k0 + tx] = f2bf(tile[tx][ty + i]);
    }
}

// ---- 256x256 8-phase GEMM, BK=64 (2 K-halves of 32), 8 waves (2m x 4n) ----
// LDS regions [buf][A/B][kh] of [256 rows][32 k] u16 (16KB each), 128KB total.
// 16B k-slots XOR-swizzled with swz(row) = (row>>1)&3  (bits independent of the
// row bank-offset bit row&1 -> lanes 0..15 of a frag read cover all 8 bank
// groups).  Applied on the global SOURCE at stage time (LDS write linear for
// global_load_lds) and on the ds_read address.  vmcnt(4) counted, never 0 in loop.
// MFMA operands SWAPPED: mfma(bfr, af) -> lane&15 = m, (lane>>4)*4+j = n, so
// each lane holds 4 consecutive n -> 8B packed dwordx2 epilogue stores.
#define AO_(c, kh) ((((c) << 2) + (kh)) << 13)
#define BO_(c, kh) ((((c) << 2) + 2 + (kh)) << 13)

__global__ __launch_bounds__(512, 1)
void gemm8p(const u16* __restrict__ A, const u16* __restrict__ Bt,
            const float* __restrict__ bias, u16* __restrict__ Y,
            int Kp, int NK, int NBN) {
    __shared__ u16 lds[65536];   // 128 KB
    const int tid = threadIdx.x;
    const int w = tid >> 6, l = tid & 63;
    const int wm = w >> 2, wn = w & 3;

    // XCD-bijective swizzle (gridDim.x % 8 == 0)
    const int cpx = gridDim.x >> 3;
    const int xg = (blockIdx.x & 7) * cpx + (blockIdx.x >> 3);
    const int bm = xg / NBN, bn = xg % NBN;
    const int brow = bm << 8, bcol = bn << 8;

    // staging: 1KB per wave-issue = 16 rows x 64B; lane l -> row l>>2, lds slot l&3;
    // inverse-swizzled global slot = (l&3) ^ swz(row) = (l&3) ^ ((l>>3)&3)
    const int srow = l >> 2;
    const int gslot = (l & 3) ^ ((l >> 3) & 3);
    const u16* ga = A  + (size_t)(brow + w * 32 + srow) * Kp + gslot * 8;
    const u16* gb = Bt + (size_t)(bcol + w * 32 + srow) * Kp + gslot * 8;
    const int ldst = w << 10;    // u16 offset of this wave's first 2KB chunk

    // frag read: row (l&15)*32 u16, swizzled slot ((l>>4) ^ ((l>>1)&3))*8 u16
    const int fl = ((l & 15) << 5) + ((((l >> 4) ^ ((l >> 1) & 3)) & 3) << 3);
    const int abase0 = (wm << 7) << 5;          // wm*128 rows * 32
    const int bbase0 = (wn << 6) << 5;          // wn*64 rows * 32

#define STG(OFF, gp, kt, kh) do {                                              \
    gload_lds16((gp) + (size_t)(kt) * 64 + (kh) * 32, &lds[(OFF) + ldst]);     \
    gload_lds16((gp) + 16 * (size_t)Kp + (size_t)(kt) * 64 + (kh) * 32,        \
                &lds[(OFF) + ldst + 512]);                                     \
} while (0)

    f32x4 acc[8][4] = {};
    bf16x8 bfr[4];

    // prologue: K-tile 0 (all 4 halves) + K-tile 1 kh0 halves
    STG(AO_(0, 0), ga, 0, 0); STG(BO_(0, 0), gb, 0, 0);
    STG(AO_(0, 1), ga, 0, 1); STG(BO_(0, 1), gb, 0, 1);
    STG(AO_(1, 0), ga, 1, 0); STG(BO_(1, 0), gb, 1, 0);
    asm volatile("s_waitcnt vmcnt(4)" ::: "memory");
    __builtin_amdgcn_s_barrier();
    asm volatile("" ::: "memory");

#define PHASE(CH, KH, LOADB, STAGECODE, VMW) do {                              \
    bf16x8 af[4];                                                              \
    { const int ab = AO_(cur, KH) + abase0 + ((CH) << 11);                     \
      _Pragma("unroll")                                                        \
      for (int mf = 0; mf < 4; ++mf)                                           \
          af[mf] = *reinterpret_cast<const bf16x8*>(&lds[ab + (mf << 9) + fl]);\
    }                                                                          \
    if (LOADB) {                                                               \
        const int bb = BO_(cur, KH) + bbase0;                                  \
        _Pragma("unroll")                                                      \
        for (int nf = 0; nf < 4; ++nf)                                         \
            bfr[nf] = *reinterpret_cast<const bf16x8*>(&lds[bb + (nf << 9) + fl]); \
    }                                                                          \
    STAGECODE;                                                                 \
    if (VMW) asm volatile("s_waitcnt vmcnt(4)" ::: "memory");                  \
    asm volatile("" ::: "memory");                                             \
    __builtin_amdgcn_s_barrier();                                              \
    asm volatile("s_waitcnt lgkmcnt(0)" ::: "memory");                         \
    __builtin_amdgcn_sched_barrier(0);                                         \
    __builtin_amdgcn_s_setprio(1);                                             \
    _Pragma("unroll")                                                          \
    for (int mf = 0; mf < 4; ++mf)                                             \
        _Pragma("unroll")                                                      \
        for (int nf = 0; nf < 4; ++nf)                                         \
            acc[(CH) * 4 + mf][nf] = __builtin_amdgcn_mfma_f32_16x16x32_bf16(  \
                bfr[nf], af[mf], acc[(CH) * 4 + mf][nf], 0, 0, 0);             \
    __builtin_amdgcn_s_setprio(0);                                             \
    __builtin_amdgcn_sched_barrier(0);                                         \
    __builtin_amdgcn_s_barrier();                                              \
    asm volatile("" ::: "memory");                                             \
} while (0)

    for (int kt = 0; kt < NK; ++kt) {
        const int cur = kt & 1;
        const int kn1 = (kt + 1 < NK) ? kt + 1 : kt;   // source clamp (dest region is dead)
        const int kn2 = (kt + 2 < NK) ? kt + 2 : kt;
        PHASE(0, 0, 1, { STG(AO_(cur ^ 1, 1), ga, kn1, 1); }, 0);
        PHASE(1, 0, 0, { STG(BO_(cur ^ 1, 1), gb, kn1, 1); }, 1);
        PHASE(0, 1, 1, { STG(AO_(cur, 0),     ga, kn2, 0); }, 0);
        PHASE(1, 1, 0, { STG(BO_(cur, 0),     gb, kn2, 0); }, 1);
    }

    asm volatile("s_waitcnt vmcnt(0)" ::: "memory");   // drain tail stages

    // epilogue (swapped D layout): m = wm*128 + (ci>>2)*64 + (ci&3)*16 + (l&15)
    //                              n = wn*64 + nf*16 + (l>>4)*4 + j
    const int m0 = brow + wm * 128 + (l & 15);
    const int n0 = bcol + wn * 64 + ((l >> 4) << 2);
    float4 bv4[4];
    #pragma unroll
    for (int nf = 0; nf < 4; ++nf)
        bv4[nf] = *reinterpret_cast<const float4*>(&bias[n0 + nf * 16]);
    #pragma unroll
    for (int ci = 0; ci < 8; ++ci) {
        const size_t mrow = (size_t)(m0 + ((ci >> 2) << 6) + ((ci & 3) << 4)) * N_;
        #pragma unroll
        for (int nf = 0; nf < 4; ++nf) {
            u32x2 p;
            p.x = (u32)f2bf(acc[ci][nf][0] + bv4[nf].x) |
                  ((u32)f2bf(acc[ci][nf][1] + bv4[nf].y) << 16);
            p.y = (u32)f2bf(acc[ci][nf][2] + bv4[nf].z) |
                  ((u32)f2bf(acc[ci][nf][3] + bv4[nf].w) << 16);
            *reinterpret_cast<u32x2*>(&Y[mrow + n0 + nf * 16]) = p;
        }
    }
#undef PHASE
#undef STG
}

// ---- chunked scan ----
__global__ void scan_p1(const u16* __restrict__ y, float* __restrict__ aprod,
                        float* __restrict__ cend) {
    const int hb = blockIdx.x & 1;
    const int chunk = (blockIdx.x >> 1) & (NC_ - 1);
    const int b = blockIdx.x >> 6;
    const int h = (hb << 9) + (threadIdx.x << 1);
    const u16* yb = y + ((size_t)b * T_ + (size_t)chunk * L_) * N_;
    float a0 = 1.f, a1 = 1.f, c0 = 0.f, c1 = 0.f;
    #pragma unroll 4
    for (int t = 0; t < L_; ++t) {
        const u32 zz = *reinterpret_cast<const u32*>(&yb[t * N_ + h]);
        const u32 ff = *reinterpret_cast<const u32*>(&yb[t * N_ + H_ + h]);
        const float f0 = sigm(bf2f((u16)ff));
        const float f1 = sigm(bf2f((u16)(ff >> 16)));
        const float z0 = fmaxf(bf2f((u16)zz), 0.f);
        const float z1 = fmaxf(bf2f((u16)(zz >> 16)), 0.f);
        c0 = f0 * z0 + (1.f - f0) * c0;  a0 *= (1.f - f0);
        c1 = f1 * z1 + (1.f - f1) * c1;  a1 *= (1.f - f1);
    }
    const size_t idx = ((size_t)b * NC_ + chunk) * H_ + h;
    *reinterpret_cast<float2*>(&aprod[idx]) = make_float2(a0, a1);
    *reinterpret_cast<float2*>(&cend[idx])  = make_float2(c0, c1);
}

__global__ void scan_p2(const float* __restrict__ aprod, const float* __restrict__ cend,
                        float* __restrict__ cin, float* __restrict__ hout, int layer) {
    const int b = blockIdx.x >> 2;
    const int h = ((blockIdx.x & 3) << 8) + threadIdx.x;
    float c = 0.f;
    #pragma unroll
    for (int k = 0; k < NC_; ++k) {
        const size_t idx = ((size_t)b * NC_ + k) * H_ + h;
        cin[idx] = c;
        c = aprod[idx] * c + cend[idx];
    }
    hout[(size_t)(((b << 1) + layer) << 10) + h] = c;
}

__global__ void scan_p3(const u16* __restrict__ y, const float* __restrict__ cin,
                        void* __restrict__ xout, int layer) {
    const int hb = blockIdx.x & 1;
    const int chunk = (blockIdx.x >> 1) & (NC_ - 1);
    const int b = blockIdx.x >> 6;
    const int h = (hb << 9) + (threadIdx.x << 1);
    const u16* yb = y + ((size_t)b * T_ + (size_t)chunk * L_) * N_;
    const size_t cidx = ((size_t)b * NC_ + chunk) * H_ + h;
    const float2 cv = *reinterpret_cast<const float2*>(&cin[cidx]);
    float c0 = cv.x, c1 = cv.y;
    u32*    xo_bf = (u32*)xout;
    float2* xo_f  = (float2*)xout;
    const size_t obase = ((size_t)b * T_ + (size_t)chunk * L_) * H_ + h;
    #pragma unroll 4
    for (int t = 0; t < L_; ++t) {
        const u32 zz = *reinterpret_cast<const u32*>(&yb[t * N_ + h]);
        const u32 ff = *reinterpret_cast<const u32*>(&yb[t * N_ + H_ + h]);
        const u32 oo = *reinterpret_cast<const u32*>(&yb[t * N_ + 2 * H_ + h]);
        const float f0 = sigm(bf2f((u16)ff));
        const float f1 = sigm(bf2f((u16)(ff >> 16)));
        const float z0 = fmaxf(bf2f((u16)zz), 0.f);
        const float z1 = fmaxf(bf2f((u16)(zz >> 16)), 0.f);
        c0 = f0 * z0 + (1.f - f0) * c0;
        c1 = f1 * z1 + (1.f - f1) * c1;
        const float o0 = sigm(bf2f((u16)oo)) * c0;
        const float o1 = sigm(bf2f((u16)(oo >> 16))) * c1;
        const size_t oi = obase + (size_t)t * H_;
        if (layer) xo_f[oi >> 1] = make_float2(o0, o1);
        else       xo_bf[oi >> 1] = (u32)f2bf(o0) | ((u32)f2bf(o1) << 16);
    }
}

extern "C" void kernel_launch(void* const* d_in, const int* in_sizes, int n_in,
                              void* d_out, int out_size, void* d_ws, size_t ws_size,
                              hipStream_t stream) {
    const float* pa = (const float*)d_in[0];
    const float* st = (const float*)d_in[1];
    const float* md = (const float*)d_in[2];
    const float* W1 = (const float*)d_in[3];
    const float* b1 = (const float*)d_in[4];
    const float* W2 = (const float*)d_in[5];
    const float* b2 = (const float*)d_in[6];
    float* out = (float*)d_out;

    char* ws = (char*)d_ws;
    const size_t y_bytes = (size_t)M_ * N_ * 2;          // 100.7 MB
    const size_t x_bytes = (size_t)M_ * 1600 * 2;        // 52.4 MB
    u16* y  = (u16*)ws;
    u16* x  = (u16*)(ws + y_bytes);
    u16* Wt = (u16*)(ws + y_bytes + x_bytes);            // 9.8 MB
    char* scr = ws + y_bytes + (size_t)M_ * H_ * 2;
    const size_t sarr = (size_t)B_ * NC_ * H_ * 4;       // 1 MB each
    float* aprod = (float*)scr;
    float* cend  = (float*)(scr + sarr);
    float* cin   = (float*)(scr + 2 * sarr);

    float* hout = out + (size_t)M_ * H_;

    const int grid_g = (M_ / 256) * (N_ / 256);          // 64*12 = 768 (%8==0)

    // ---- layer 1 ----
    concat_cast<<<M_, 256, 0, stream>>>(pa, st, md, x);
    wtrans<<<dim3(N_ / 32, 50), 256, 0, stream>>>(W1, Wt, 1591, 1600);
    gemm8p<<<grid_g, 512, 0, stream>>>(x, Wt, b1, y, 1600, 25, N_ / 256);
    scan_p1<<<B_ * NC_ * 2, 256, 0, stream>>>(y, aprod, cend);
    scan_p2<<<32, 256, 0, stream>>>(aprod, cend, cin, hout, 0);
    scan_p3<<<B_ * NC_ * 2, 256, 0, stream>>>(y, cin, x, 0);   // bf16 x2 into x

    // ---- layer 2 ----
    wtrans<<<dim3(N_ / 32, 32), 256, 0, stream>>>(W2, Wt, 1024, 1024);
    gemm8p<<<grid_g, 512, 0, stream>>>(x, Wt, b2, y, 1024, 16, N_ / 256);
    scan_p1<<<B_ * NC_ * 2, 256, 0, stream>>>(y, aprod, cend);
    scan_p2<<<32, 256, 0, stream>>>(aprod, cend, cin, hout, 1);
    scan_p3<<<B_ * NC_ * 2, 256, 0, stream>>>(y, cin, out, 1);
}